// Round 5
// baseline (265.405 us; speedup 1.0000x reference)
//
#include <hip/hip_runtime.h>
#include <hip/hip_bf16.h>

#define B_N 32
#define C_K 512
#define T_N 1024
#define D_M 512

constexpr int BM = 128, BN = 128, BK = 32;
constexpr int SA = 36;            // shorts per LDS row (72B): rows rotate 18 banks
constexpr int KSTEPS = C_K / BK;  // 16

typedef __attribute__((ext_vector_type(4))) float  floatx4;
typedef __attribute__((ext_vector_type(4))) short  shortx4;
typedef __attribute__((ext_vector_type(8))) short  shortx8;
typedef __attribute__((ext_vector_type(2))) unsigned int uintx2;

__device__ __forceinline__ unsigned pk2(float a, float b) {
  __hip_bfloat162 h = __float22bfloat162_rn(make_float2(a, b));
  union { __hip_bfloat162 v; unsigned u; } c; c.v = h; return c.u;
}

// Raw workgroup barrier: LDS ops must complete (lgkmcnt 0) but global
// loads-to-register stay IN FLIGHT across it (__syncthreads drains vmcnt(0),
// which caps the pipeline at depth 1 = the measured in-flight-bytes limit).
__device__ __forceinline__ void wg_barrier() {
  asm volatile("s_waitcnt lgkmcnt(0)" ::: "memory");
  __builtin_amdgcn_s_barrier();
  __builtin_amdgcn_sched_barrier(0);
}

// out[b,d,t] = sum_c x[b,c,t] * W[sub[b],c,d] + bias[sub[b],d]
// Per-b GEMM: A = W[nb] (K x M, m-contig), B = X[b] (K x N, n-contig)
//
// LDS: [row][k] bf16, SA=36 shorts/row. 8B k-chunks XOR-swizzled with
// s(row) = (row>>4)&3: phys_chunk = c ^ s.
//   Writes (row 4mg+r): s = l15>>2 -> 4 lanes/b64-pair = floor.
//   Reads (row wm+16i+l15): s = i (wave-uniform) -> 4 lanes/pair = floor.
//   Verified round 3: SQ_LDS_BANK_CONFLICT = 0, FETCH 81.6->48.7MB.
//
// Pipeline: depth-2 register prefetch across raw barriers (round 5).
// Rationale: depth-1 sustains only ~12 B/cy/CU of staging traffic (192
// dwordx4 in flight x 16B / ~250cy latency) = the measured issue rate;
// the kernel is outstanding-load limited. Rounds 1-2 appeared to refute
// depth-2 but were confounded by a BROKEN read swizzle (10.5M read-side
// conflict cycles on the lgkmcnt->MFMA critical path). This is the clean
// test: depth is the only variable vs round 3/4, conflicts at 0.
__global__ __launch_bounds__(256, 4)
void subject_gemm(const float* __restrict__ x, const int* __restrict__ subjects,
                  const float* __restrict__ weights, const float* __restrict__ bias,
                  float* __restrict__ out)
{
  __shared__ __align__(16) short lds_a[2][BM * SA]; // [m][k] bf16 (chunk-swizzled)
  __shared__ __align__(16) short lds_b[2][BN * SA]; // [n][k]

  // XCD-aware swizzle: all 32 tiles of a batch land on one XCD.
  const int bid  = blockIdx.x;
  const int xcd  = bid & 7;
  const int s    = bid >> 3;           // 0..127
  const int b    = xcd * 4 + (s & 3);  // 4 batches per XCD
  const int tile = s >> 2;             // 0..31
  const int tm = tile >> 3, tn = tile & 7;
  const int m0 = tm * BM, n0 = tn * BN;
  const int nb = subjects[b];

  const float* __restrict__ Wp = weights + (size_t)nb * C_K * D_M; // [k][m]
  const float* __restrict__ Xp = x + (size_t)b * C_K * T_N;        // [k][n]

  const int tid  = threadIdx.x;
  const int lane = tid & 63;
  const int wave = tid >> 6;

  // ---- staging role: waves 0-1 stage A, waves 2-3 stage B ----
  const bool isA = (wave < 2);
  const int  mg  = (wave & 1) * 16 + (lane & 15); // rows 4*mg..4*mg+3
  const int  oct = lane >> 4;                     // k = 8*oct + jj
  const float* gsrc = isA ? (Wp + (size_t)(8 * oct) * D_M + (m0 + 4 * mg))
                          : (Xp + (size_t)(8 * oct) * T_N + (n0 + 4 * mg));
  const int gs = isA ? D_M : T_N;
  const int sw  = (mg >> 2) & 3;                  // s(row)=(row>>4)&3
  const int cLo = 4 * ((2 * oct) ^ sw);           // phys offset of logical chunk 2oct
  const int cHi = 4 * ((2 * oct + 1) ^ sw);
  short* const wbase = (isA ? &lds_a[0][0] : &lds_b[0][0]) + (4 * mg) * SA;
  constexpr int BUFO = BM * SA;

  // ---- compute role: 4 waves, 64x64 tiles ----
  const int wm = (wave & 1) * 64, wn = (wave >> 1) * 64;
  const int l15 = lane & 15, q = lane >> 4;

  floatx4 acc[4][4] = {};
  floatx4 vA[8], vB[8];                           // depth-2 register prefetch

  auto loads = [&](floatx4 (&v)[8]) {
    #pragma unroll
    for (int jj = 0; jj < 8; ++jj)
      v[jj] = *(const floatx4*)(gsrc + (size_t)jj * gs);
    gsrc += (size_t)BK * gs;
  };
  auto cvt_store = [&](const floatx4 (&v)[8], int p) {
    short* wdst = wbase + p * BUFO;
    #pragma unroll
    for (int r = 0; r < 4; ++r) {
      uintx2 lo = { pk2(v[0][r], v[1][r]), pk2(v[2][r], v[3][r]) };
      uintx2 hi = { pk2(v[4][r], v[5][r]), pk2(v[6][r], v[7][r]) };
      *(uintx2*)(wdst + r * SA + cLo) = lo;
      *(uintx2*)(wdst + r * SA + cHi) = hi;
    }
  };
  auto compute = [&](int p) {
    const short* pa = &lds_a[p][0] + (wm + l15) * SA;
    const short* pb = &lds_b[p][0] + (wn + l15) * SA;
    shortx8 af[4], bg[4];
    #pragma unroll
    for (int i = 0; i < 4; ++i) {
      const int rLo = 4 * ((2 * q) ^ i);
      const int rHi = 4 * ((2 * q + 1) ^ i);
      shortx4 alo = *(const shortx4*)(pa + 16 * i * SA + rLo);
      shortx4 ahi = *(const shortx4*)(pa + 16 * i * SA + rHi);
      shortx4 blo = *(const shortx4*)(pb + 16 * i * SA + rLo);
      shortx4 bhi = *(const shortx4*)(pb + 16 * i * SA + rHi);
      af[i] = __builtin_shufflevector(alo, ahi, 0, 1, 2, 3, 4, 5, 6, 7);
      bg[i] = __builtin_shufflevector(blo, bhi, 0, 1, 2, 3, 4, 5, 6, 7);
    }
    #pragma unroll
    for (int i = 0; i < 4; ++i)
      #pragma unroll
      for (int j = 0; j < 4; ++j)
        acc[i][j] = __builtin_amdgcn_mfma_f32_16x16x32_bf16(af[i], bg[j], acc[i][j], 0, 0, 0);
  };

  // ---- prologue: 2 tiles in flight ----
  loads(vA);            // tile 0
  loads(vB);            // tile 1 (stays in flight across barriers)
  cvt_store(vA, 0);     // tile 0 -> buf0 (waits vmcnt(8): vB still in flight)

  // ---- main loop: every tile's loads get >= 1 full K-step of flight ----
  #pragma unroll 1
  for (int kk = 0; kk < KSTEPS - 2; kk += 2) {
    wg_barrier();       // buf0 ready; vA (next-next tile) stays in flight
    loads(vA);          // tile kk+2
    compute(0);         // tile kk
    cvt_store(vB, 1);   // tile kk+1 (waits vmcnt(8): only vA outstanding)
    wg_barrier();
    loads(vB);          // tile kk+3
    compute(1);         // tile kk+1
    cvt_store(vA, 0);   // tile kk+2
  }
  wg_barrier();
  compute(0);           // tile 14
  cvt_store(vB, 1);     // tile 15
  wg_barrier();
  compute(1);           // tile 15

  // ---- epilogue: col = lane&15 (t), row = 4q + r (d) ----
  float* __restrict__ O = out + (size_t)b * D_M * T_N;
  const float* __restrict__ bb = bias + (size_t)nb * D_M;
  #pragma unroll
  for (int i = 0; i < 4; ++i) {
    #pragma unroll
    for (int r = 0; r < 4; ++r) {
      const int d = m0 + wm + 16 * i + 4 * q + r;
      const float bv = bb[d];
      #pragma unroll
      for (int j = 0; j < 4; ++j) {
        const int t = n0 + wn + 16 * j + l15;
        O[(size_t)d * T_N + t] = acc[i][j][r] + bv;
      }
    }
  }
}

extern "C" void kernel_launch(void* const* d_in, const int* in_sizes, int n_in,
                              void* d_out, int out_size, void* d_ws, size_t ws_size,
                              hipStream_t stream) {
  const float* x        = (const float*)d_in[0];
  const int*   subjects = (const int*)d_in[1];
  const float* weights  = (const float*)d_in[2];
  const float* bias     = (const float*)d_in[3];
  float* out = (float*)d_out;
  (void)in_sizes; (void)n_in; (void)out_size; (void)d_ws; (void)ws_size;

  dim3 grid(B_N * 4 * 8); // 1024 blocks: 32 b x 4 tm x 8 tn
  dim3 block(256);
  hipLaunchKernelGGL(subject_gemm, grid, block, 0, stream, x, subjects, weights, bias, out);
}

// Round 6
// 177.087 us; speedup vs baseline: 1.4987x; 1.4987x over previous
//
#include <hip/hip_runtime.h>
#include <hip/hip_bf16.h>

#define B_N 32
#define C_K 512
#define T_N 1024
#define D_M 512

constexpr int BM = 128, BN = 128, BK = 32;
constexpr int SA = 32;            // shorts per LDS row (64B): 32KB/block -> 4 blocks/CU
constexpr int KSTEPS = C_K / BK;  // 16

typedef __attribute__((ext_vector_type(4))) float  floatx4;
typedef __attribute__((ext_vector_type(8))) short  shortx8;
typedef __attribute__((ext_vector_type(4))) unsigned int uintx4;

__device__ __forceinline__ unsigned pk2(float a, float b) {
  __hip_bfloat162 h = __float22bfloat162_rn(make_float2(a, b));
  union { __hip_bfloat162 v; unsigned u; } c; c.v = h; return c.u;
}

// out[b,d,t] = sum_c x[b,c,t] * W[sub[b],c,d] + bias[sub[b],d]
// Per-b GEMM: A = W[nb] (K x M, m-contig), B = X[b] (K x N, n-contig)
//
// LDS (round 6): [row][k] bf16, SA=32 shorts (64B rows, no pad) = 32,768 B
// total -> targets 4 blocks/CU (rounds 3-4 showed 36,864B caps residency at 3:
// pool < 147KB; this probes pool >= 131,072).
// Swizzle on 16B k-chunks: phys_q = q ^ ((row>>4)&3).
//   Reads: ONE ds_read_b128 per fragment, slot = 4*(l15&1) + (q^i) -> 8
//     lanes/16B-slot = exact b128 floor. Conflict-free on the critical path.
//   Writes: ds_write_b128 per row, 16 lanes/slot = 2x floor — unavoidable with
//     64B rows, and proven off-critical-path (round 0->3 A/B: removing 4.19M
//     write-conflict cycles changed dur by ~0).
//
// Pipeline: depth-1, __syncthreads. Depth-2 register prefetch is structurally
// dead: needs +64 VGPRs -> spills to scratch (round 5: WRITE 65->294MB, 2.4x
// slowdown). Within-step overlap only (loads issued post-barrier, waited at cvt).
__global__ __launch_bounds__(256, 4)
void subject_gemm(const float* __restrict__ x, const int* __restrict__ subjects,
                  const float* __restrict__ weights, const float* __restrict__ bias,
                  float* __restrict__ out)
{
  __shared__ __align__(16) short lds_a[2][BM * SA]; // [m][k] bf16 (chunk16-swizzled)
  __shared__ __align__(16) short lds_b[2][BN * SA]; // [n][k]

  // XCD-aware swizzle: all 32 tiles of a batch land on one XCD.
  const int bid  = blockIdx.x;
  const int xcd  = bid & 7;
  const int s    = bid >> 3;           // 0..127
  const int b    = xcd * 4 + (s & 3);  // 4 batches per XCD
  const int tile = s >> 2;             // 0..31
  const int tm = tile >> 3, tn = tile & 7;
  const int m0 = tm * BM, n0 = tn * BN;
  const int nb = subjects[b];

  const float* __restrict__ Wp = weights + (size_t)nb * C_K * D_M; // [k][m]
  const float* __restrict__ Xp = x + (size_t)b * C_K * T_N;        // [k][n]

  const int tid  = threadIdx.x;
  const int lane = tid & 63;
  const int wave = tid >> 6;

  // ---- staging role: waves 0-1 stage A, waves 2-3 stage B ----
  const bool isA = (wave < 2);
  const int  mg  = (wave & 1) * 16 + (lane & 15); // rows 4*mg..4*mg+3
  const int  oct = lane >> 4;                     // k-chunk16; k = 8*oct + jj
  const float* gsrc = isA ? (Wp + (size_t)(8 * oct) * D_M + (m0 + 4 * mg))
                          : (Xp + (size_t)(8 * oct) * T_N + (n0 + 4 * mg));
  const int gs = isA ? D_M : T_N;
  const int sw   = (mg >> 2) & 3;                 // s(row)=(row>>4)&3 for rows 4mg..4mg+3
  const int cOff = 8 * (oct ^ sw);                // short offset of phys chunk16
  short* const wbase = (isA ? &lds_a[0][0] : &lds_b[0][0]) + (4 * mg) * SA + cOff;
  constexpr int BUFO = BM * SA;

  // ---- compute role: 4 waves, 64x64 tiles ----
  const int wm = (wave & 1) * 64, wn = (wave >> 1) * 64;
  const int l15 = lane & 15, q = lane >> 4;

  floatx4 acc[4][4] = {};
  floatx4 v[8];

  // ---- prologue: load+stage tile 0 into buf 0 ----
  #pragma unroll
  for (int jj = 0; jj < 8; ++jj)
    v[jj] = *(const floatx4*)(gsrc + (size_t)jj * gs);
  gsrc += (size_t)BK * gs;
  #pragma unroll
  for (int r = 0; r < 4; ++r) {
    uintx4 pk = { pk2(v[0][r], v[1][r]), pk2(v[2][r], v[3][r]),
                  pk2(v[4][r], v[5][r]), pk2(v[6][r], v[7][r]) };
    *(uintx4*)(wbase + r * SA) = pk;
  }

  for (int ks = 0; ks < KSTEPS; ++ks) {
    const int p = ks & 1;
    __syncthreads(); // buf p ready; drains vmem (nothing outstanding here)

    // issue next tile's loads AFTER the barrier so they stay in flight
    // across frag reads + MFMA (vmcnt wait lands at the cvt block below)
    if (ks + 1 < KSTEPS) {
      #pragma unroll
      for (int jj = 0; jj < 8; ++jj)
        v[jj] = *(const floatx4*)(gsrc + (size_t)jj * gs);
      gsrc += (size_t)BK * gs;
    }

    // fragments from buf p: single b128 each, phys chunk = q ^ i (wave-uniform)
    const short* pa = &lds_a[p][0] + (wm + l15) * SA;
    const short* pb = &lds_b[p][0] + (wn + l15) * SA;
    shortx8 af[4], bg[4];
    #pragma unroll
    for (int i = 0; i < 4; ++i) {
      af[i] = *(const shortx8*)(pa + 16 * i * SA + 8 * (q ^ i));
      bg[i] = *(const shortx8*)(pb + 16 * i * SA + 8 * (q ^ i));
    }
    #pragma unroll
    for (int i = 0; i < 4; ++i)
      #pragma unroll
      for (int j = 0; j < 4; ++j)
        acc[i][j] = __builtin_amdgcn_mfma_f32_16x16x32_bf16(af[i], bg[j], acc[i][j], 0, 0, 0);

    // cvt (vmcnt wait lands HERE, after MFMA) + stage into buf p^1
    if (ks + 1 < KSTEPS) {
      short* wdst = wbase + (p ^ 1) * BUFO;
      #pragma unroll
      for (int r = 0; r < 4; ++r) {
        uintx4 pk = { pk2(v[0][r], v[1][r]), pk2(v[2][r], v[3][r]),
                      pk2(v[4][r], v[5][r]), pk2(v[6][r], v[7][r]) };
        *(uintx4*)(wdst + r * SA) = pk;
      }
    }
  }

  // ---- epilogue: col = lane&15 (t), row = 4q + r (d) ----
  float* __restrict__ O = out + (size_t)b * D_M * T_N;
  const float* __restrict__ bb = bias + (size_t)nb * D_M;
  #pragma unroll
  for (int i = 0; i < 4; ++i) {
    #pragma unroll
    for (int r = 0; r < 4; ++r) {
      const int d = m0 + wm + 16 * i + 4 * q + r;
      const float bv = bb[d];
      #pragma unroll
      for (int j = 0; j < 4; ++j) {
        const int t = n0 + wn + 16 * j + l15;
        O[(size_t)d * T_N + t] = acc[i][j][r] + bv;
      }
    }
  }
}

extern "C" void kernel_launch(void* const* d_in, const int* in_sizes, int n_in,
                              void* d_out, int out_size, void* d_ws, size_t ws_size,
                              hipStream_t stream) {
  const float* x        = (const float*)d_in[0];
  const int*   subjects = (const int*)d_in[1];
  const float* weights  = (const float*)d_in[2];
  const float* bias     = (const float*)d_in[3];
  float* out = (float*)d_out;
  (void)in_sizes; (void)n_in; (void)out_size; (void)d_ws; (void)ws_size;

  dim3 grid(B_N * 4 * 8); // 1024 blocks: 32 b x 4 tm x 8 tn = 4/CU target
  dim3 block(256);
  hipLaunchKernelGGL(subject_gemm, grid, block, 0, stream, x, subjects, weights, bias, out);
}